// Round 9
// baseline (445.920 us; speedup 1.0000x reference)
//
#include <hip/hip_runtime.h>
#include <hip/hip_bf16.h>
#include <math.h>

typedef __bf16 bf16_t;
typedef __bf16 bf16x4 __attribute__((ext_vector_type(4)));
typedef int i32x4 __attribute__((ext_vector_type(4)));

#define AS1 __attribute__((address_space(1)))
#define AS3 __attribute__((address_space(3)))

__device__ __forceinline__ void gl_lds16(const char* g, char* l) {
  __builtin_amdgcn_global_load_lds((const AS1 void*)g, (AS3 void*)l, 16, 0, 0);
}

__device__ __forceinline__ unsigned pack4i(float a, float b, float c, float d) {
  return ((unsigned)(unsigned char)(int)a) | ((unsigned)(unsigned char)(int)b << 8) |
         ((unsigned)(unsigned char)(int)c << 16) | ((unsigned)(unsigned char)(int)d << 24);
}

// ---------- block reductions (256 threads = 4 waves) ----------
__device__ __forceinline__ float block_sum_f(float v) {
  __shared__ float sb[4];
  #pragma unroll
  for (int o = 32; o; o >>= 1) v += __shfl_xor(v, o);
  if ((threadIdx.x & 63) == 0) sb[threadIdx.x >> 6] = v;
  __syncthreads();
  v = sb[0] + sb[1] + sb[2] + sb[3];
  __syncthreads();
  return v;
}
__device__ __forceinline__ float block_max_f(float v) {
  __shared__ float sm[4];
  #pragma unroll
  for (int o = 32; o; o >>= 1) v = fmaxf(v, __shfl_xor(v, o));
  if ((threadIdx.x & 63) == 0) sm[threadIdx.x >> 6] = v;
  __syncthreads();
  v = fmaxf(fmaxf(sm[0], sm[1]), fmaxf(sm[2], sm[3]));
  __syncthreads();
  return v;
}

// ---------- weight absmean (f64 accumulation, two-pass, deterministic) ----------
__global__ __launch_bounds__(256) void wabs_partial(const float* __restrict__ w, int n4,
                                                    double* __restrict__ part) {
  const float4* w4 = (const float4*)w;
  double s = 0.0;
  const int stride = gridDim.x * blockDim.x;
  for (int i = blockIdx.x * blockDim.x + threadIdx.x; i < n4; i += stride) {
    float4 v = w4[i];
    s += (double)fabsf(v.x) + (double)fabsf(v.y) + (double)fabsf(v.z) + (double)fabsf(v.w);
  }
  #pragma unroll
  for (int o = 32; o; o >>= 1) s += __shfl_xor(s, o);
  __shared__ double sd[4];
  if ((threadIdx.x & 63) == 0) sd[threadIdx.x >> 6] = s;
  __syncthreads();
  if (threadIdx.x == 0) part[blockIdx.x] = sd[0] + sd[1] + sd[2] + sd[3];
}

__global__ __launch_bounds__(256) void wabs_final(const double* __restrict__ part, int np,
                                                  double n, float* __restrict__ fwout) {
  double s = 0.0;
  for (int i = threadIdx.x; i < np; i += blockDim.x) s += part[i];
  #pragma unroll
  for (int o = 32; o; o >>= 1) s += __shfl_xor(s, o);
  __shared__ double sd[4];
  if ((threadIdx.x & 63) == 0) sd[threadIdx.x >> 6] = s;
  __syncthreads();
  if (threadIdx.x == 0) {
    double mean = (sd[0] + sd[1] + sd[2] + sd[3]) / n;
    fwout[0] = (float)fmax(mean, 1e-5);
  }
}

// ---------- ternary weight quantization -> int8 {-1,0,1} ----------
__global__ __launch_bounds__(256) void quant_w(const float* __restrict__ w,
                                               const float* __restrict__ fw,
                                               char* __restrict__ wq, int n4) {
  int i = blockIdx.x * blockDim.x + threadIdx.x;
  if (i >= n4) return;
  const float s = 1.0f / fw[0];
  float4 v = ((const float4*)w)[i];
  ((unsigned*)wq)[i] = pack4i(fminf(fmaxf(rintf(v.x * s), -1.f), 1.f),
                              fminf(fmaxf(rintf(v.y * s), -1.f), 1.f),
                              fminf(fmaxf(rintf(v.z * s), -1.f), 1.f),
                              fminf(fmaxf(rintf(v.w * s), -1.f), 1.f));
}

// ---------- rms_norm + act_quant of x rows (K = 2048) -> int8 + scale ----------
__global__ __launch_bounds__(256) void rms_quant_x(const float* __restrict__ x,
                                                   char* __restrict__ xq,
                                                   float* __restrict__ fx, int K) {
  const int row = blockIdx.x, t = threadIdx.x;
  const size_t base = (size_t)row * K;
  float v[8];
  float ss = 0.f;
  #pragma unroll
  for (int j = 0; j < 2; j++) {
    float4 lv = *(const float4*)(x + base + j * 1024 + t * 4);
    v[j*4+0] = lv.x; v[j*4+1] = lv.y; v[j*4+2] = lv.z; v[j*4+3] = lv.w;
  }
  #pragma unroll
  for (int i = 0; i < 8; i++) ss += v[i] * v[i];
  ss = block_sum_f(ss);
  const float r = 1.0f / sqrtf(ss / (float)K + 1e-5f);
  float amax = 0.f;
  #pragma unroll
  for (int i = 0; i < 8; i++) { v[i] *= r; amax = fmaxf(amax, fabsf(v[i])); }
  amax = block_max_f(amax);
  amax = fmaxf(amax, 1e-5f);
  const float scale = 127.0f / amax;
  #pragma unroll
  for (int j = 0; j < 2; j++) {
    float q[4];
    #pragma unroll
    for (int e = 0; e < 4; e++)
      q[e] = fminf(fmaxf(rintf(v[j*4+e] * scale), -128.f), 127.f);
    *(unsigned*)(xq + base + j * 1024 + t * 4) = pack4i(q[0], q[1], q[2], q[3]);
  }
  if (t == 0) fx[row] = amax / 127.0f;
}

// ---------- LayerNorm -> rms_norm -> act_quant: bf16 h rows -> int8 hq (N = 8192) ----
__global__ __launch_bounds__(256) void ln_rms_quant(const bf16_t* __restrict__ h,
                                                    char* __restrict__ hq,
                                                    const float* __restrict__ g,
                                                    const float* __restrict__ bb,
                                                    float* __restrict__ fh, int N) {
  const int row = blockIdx.x, t = threadIdx.x;
  const size_t base = (size_t)row * N;
  float v[32];
  float s = 0.f, ss = 0.f;
  #pragma unroll
  for (int j = 0; j < 8; j++) {
    const int col = j * 1024 + t * 4;
    bf16x4 q = *(const bf16x4*)(h + base + col);
    v[j*4+0] = (float)q[0]; v[j*4+1] = (float)q[1];
    v[j*4+2] = (float)q[2]; v[j*4+3] = (float)q[3];
  }
  #pragma unroll
  for (int i = 0; i < 32; i++) { s += v[i]; ss += v[i] * v[i]; }
  s = block_sum_f(s);
  ss = block_sum_f(ss);
  const float mu = s / (float)N;
  const float var = ss / (float)N - mu * mu;
  const float rstd = 1.0f / sqrtf(var + 1e-5f);
  float ss2 = 0.f;
  #pragma unroll
  for (int j = 0; j < 8; j++) {
    const int col = j * 1024 + t * 4;
    float4 gv = *(const float4*)(g + col);
    float4 bv = *(const float4*)(bb + col);
    float y0 = (v[j*4+0] - mu) * rstd * gv.x + bv.x;
    float y1 = (v[j*4+1] - mu) * rstd * gv.y + bv.y;
    float y2 = (v[j*4+2] - mu) * rstd * gv.z + bv.z;
    float y3 = (v[j*4+3] - mu) * rstd * gv.w + bv.w;
    v[j*4+0] = y0; v[j*4+1] = y1; v[j*4+2] = y2; v[j*4+3] = y3;
    ss2 += y0*y0 + y1*y1 + y2*y2 + y3*y3;
  }
  ss2 = block_sum_f(ss2);
  const float r2 = 1.0f / sqrtf(ss2 / (float)N + 1e-5f);
  float amax = 0.f;
  #pragma unroll
  for (int i = 0; i < 32; i++) { v[i] *= r2; amax = fmaxf(amax, fabsf(v[i])); }
  amax = block_max_f(amax);
  amax = fmaxf(amax, 1e-5f);
  const float scale = 127.0f / amax;
  #pragma unroll
  for (int j = 0; j < 8; j++) {
    const int col = j * 1024 + t * 4;
    float q[4];
    #pragma unroll
    for (int e = 0; e < 4; e++)
      q[e] = fminf(fmaxf(rintf(v[j*4+e] * scale), -128.f), 127.f);
    *(unsigned*)(hq + base + col) = pack4i(q[0], q[1], q[2], q[3]);
  }
  if (t == 0) fh[row] = amax / 127.0f;
}

// ============ 256x256 i8 GEMM, 2-fat-phase schedule (B stored [N][K]) ============
// 8 waves (2Mx4N), wave out 128x64. BK=128 -> 2 k-instr (mfma_i32_16x16x64_i8).
// LDS: A = [2 buf][2 half][8 rowblk][16 rows][8 x 16B slots] = 64KB at 0; B same at
// 65536. Slot swizzle phys_slot = slot ^ (row&7) (conflict-free b128); staged via
// pre-swizzled global source col, linear LDS dest.
// Per K-tile, 2 phases x {stage 4; vmcnt(6); BAR; reads; 32 MFMA; BAR}:
//   ph0: stage {Alo,Blo}(t+1); VM(6); BAR; read bL(4)+afL(8)+bH(4);
//        MFMA (0,0)+(0,1); BAR
//   ph1: stage {Bhi,Ahi}(t+1); VM(6); BAR; read afH(8);
//        MFMA (1,1)+(1,0); BAR
// Guard arithmetic (issue order AloBlo | BhiAhi, 4 per batch): at (t,ph0), up to 12
// outstanding; VM(6) forces oldest 6 = AloBlo(t)+Bhi(t) = exactly ph0's read set.
// At (t,ph1), <=10 outstanding; VM(6) forces Ahi(t). Tails: VM(2) / VM(0).
// WAR: every staged region's LDS reads are consumed >=1 barrier before re-stage
// (post-MFMA barriers guarantee it). MFMA bursts (32) exceed per-phase drains.
template<int EPI, bool STORE_BF16>
__global__ __launch_bounds__(512, 2) void gemm256(const char* __restrict__ A,
                                                  const char* __restrict__ B,
                                                  const float* __restrict__ rowf,
                                                  const float* __restrict__ wf,
                                                  const float* __restrict__ bias,
                                                  float* __restrict__ Cf,
                                                  bf16_t* __restrict__ Cb,
                                                  int M, int N, int K) {
  __shared__ char smem[131072];

  const int ntile = N >> 8;
  const int cpx = gridDim.x >> 3;                 // blocks per XCD (grid % 8 == 0)
  const int bid = blockIdx.x;
  const int xcd = bid & 7, local = bid >> 3;
  int wg;
  const int mrows = cpx / ntile;                  // L2-aware: bm varies fastest
  if (mrows * ntile == cpx && mrows > 0) {
    const int bm_l = local % mrows, bn_i = local / mrows;
    wg = (xcd * mrows + bm_l) * ntile + bn_i;
  } else {
    wg = xcd * cpx + local;
  }
  const int bm = wg / ntile, bn = wg % ntile;
  const int tm = bm << 8, tn = bn << 8;

  const int tid = threadIdx.x;
  const int w = tid >> 6, lane = tid & 63;
  const int wm = w >> 2, wn = w & 3;
  const int ln15 = lane & 15;

  // staging: wave w owns rowblk w (16 rows x 128B = 2 gl_lds) of each half.
  const int srow = lane >> 3;                                  // 0..7
  const int scol = ((lane & 7) ^ srow) << 4;                   // pre-swizzled slot
  const size_t KS = (size_t)K;
  const char* pAst = A + (size_t)(tm + w * 16 + srow) * KS + scol;
  const char* pBst = B + (size_t)(tn + w * 16 + srow) * KS + scol;
  const size_t hiO = (size_t)128 * KS;                         // +128 rows (hi half)
  const size_t r8 = (size_t)8 * KS;                            // +8 rows (2nd gl_lds)
  const int dW = w * 2048;                                     // wave rowblk offset

  // frag read: row ln15, k-slot (kk*4 + lane>>4), phys = slot ^ (ln15&7)
  int foffk[2];
  #pragma unroll
  for (int kk = 0; kk < 2; kk++)
    foffk[kk] = ln15 * 128 + ((((kk << 2) + (lane >> 4)) ^ (ln15 & 7)) << 4);

  i32x4 acc[8][4] = {};
  const int NT = K >> 7;                                       // K-tiles of 128

#define SB __builtin_amdgcn_sched_barrier(0)
#define BAR { SB; __builtin_amdgcn_s_barrier(); SB; }
#define ST_A(bb, hh, kt) { const char* p = pAst + ((hh) ? hiO : 0) + (size_t)(kt) * 128; \
    char* dst = smem + (bb) * 32768 + (hh) * 16384 + dW;                                 \
    gl_lds16(p, dst); gl_lds16(p + r8, dst + 1024); }
#define ST_B(bb, hh, kt) { const char* p = pBst + ((hh) ? hiO : 0) + (size_t)(kt) * 128; \
    char* dst = smem + 65536 + (bb) * 32768 + (hh) * 16384 + dW;                         \
    gl_lds16(p, dst); gl_lds16(p + r8, dst + 1024); }
#define MM(AF, BF, MB, NB)                                                   \
  _Pragma("unroll") for (int kk = 0; kk < 2; kk++)                           \
    _Pragma("unroll") for (int m4 = 0; m4 < 4; m4++)                         \
      _Pragma("unroll") for (int n2 = 0; n2 < 2; n2++)                       \
        acc[(MB)+m4][(NB)+n2] = __builtin_amdgcn_mfma_i32_16x16x64_i8(       \
            AF[m4][kk], BF[n2][kk], acc[(MB)+m4][(NB)+n2], 0, 0, 0);
#define VM(n) asm volatile("s_waitcnt vmcnt(" #n ")" ::: "memory")

  // prologue: stage tile0 in batch order {Alo,Blo},{Bhi,Ahi}
  ST_A(0, 0, 0); ST_B(0, 0, 0); ST_B(0, 1, 0); ST_A(0, 1, 0);

  for (int t = 0; t < NT; ++t) {
    const int b = t & 1, nb = b ^ 1;
    const char* sA = smem + b * 32768;
    const char* sB = smem + 65536 + b * 32768;
    i32x4 afL[4][2], afH[4][2], bL[2][2], bH[2][2];
    // ---- ph0: quadrants (0,0) + (0,1)
    if (t + 1 < NT) { ST_A(nb, 0, t + 1); ST_B(nb, 0, t + 1); VM(6); }
    else            { VM(2); }
    BAR;
    #pragma unroll
    for (int n2 = 0; n2 < 2; n2++)
      #pragma unroll
      for (int kk = 0; kk < 2; kk++)
        bL[n2][kk] = *(const i32x4*)(sB + (wn * 2 + n2) * 2048 + foffk[kk]);
    #pragma unroll
    for (int m4 = 0; m4 < 4; m4++)
      #pragma unroll
      for (int kk = 0; kk < 2; kk++)
        afL[m4][kk] = *(const i32x4*)(sA + (wm * 4 + m4) * 2048 + foffk[kk]);
    #pragma unroll
    for (int n2 = 0; n2 < 2; n2++)
      #pragma unroll
      for (int kk = 0; kk < 2; kk++)
        bH[n2][kk] = *(const i32x4*)(sB + 16384 + (wn * 2 + n2) * 2048 + foffk[kk]);
    __builtin_amdgcn_s_setprio(1);
    MM(afL, bL, 0, 0);
    MM(afL, bH, 0, 2);
    __builtin_amdgcn_s_setprio(0);
    BAR;
    // ---- ph1: quadrants (1,1) + (1,0)
    if (t + 1 < NT) { ST_B(nb, 1, t + 1); ST_A(nb, 1, t + 1); VM(6); }
    else            { VM(0); }
    BAR;
    #pragma unroll
    for (int m4 = 0; m4 < 4; m4++)
      #pragma unroll
      for (int kk = 0; kk < 2; kk++)
        afH[m4][kk] = *(const i32x4*)(sA + 16384 + (wm * 4 + m4) * 2048 + foffk[kk]);
    __builtin_amdgcn_s_setprio(1);
    MM(afH, bH, 4, 2);
    MM(afH, bL, 4, 0);
    __builtin_amdgcn_s_setprio(0);
    BAR;
  }
#undef ST_A
#undef ST_B
#undef MM
#undef VM

  // ---- epilogue: dequant + bias (+ SiLU+GELU) ----
  const float fwv = wf[0];
  const int rq = (lane >> 4) << 2;
  float rsc[8][4];
  #pragma unroll
  for (int m = 0; m < 8; m++)
    #pragma unroll
    for (int r = 0; r < 4; r++)
      rsc[m][r] = rowf[tm + (m >> 2) * 128 + wm * 64 + (m & 3) * 16 + rq + r] * fwv;

  #pragma unroll
  for (int m = 0; m < 8; m++) {
    #pragma unroll
    for (int n = 0; n < 4; n++) {
      const int col = tn + (n >> 1) * 128 + wn * 32 + (n & 1) * 16 + ln15;
      const float bv = bias[col];
      #pragma unroll
      for (int r = 0; r < 4; r++) {
        const int row = tm + (m >> 2) * 128 + wm * 64 + (m & 3) * 16 + rq + r;
        float val = (float)acc[m][n][r] * rsc[m][r] + bv;
        if (EPI == 1) {
          float sl = val / (1.0f + __expf(-val));                     // SiLU
          val = 0.5f * sl * (1.0f + erff(sl * 0.70710678118654752f)); // exact GELU
        }
        if (STORE_BF16) Cb[(size_t)row * N + col] = (bf16_t)val;
        else            Cf[(size_t)row * N + col] = val;
      }
    }
  }
}

extern "C" void kernel_launch(void* const* d_in, const int* in_sizes, int n_in,
                              void* d_out, int out_size, void* d_ws, size_t ws_size,
                              hipStream_t stream) {
  const float* x   = (const float*)d_in[0];
  const float* w1  = (const float*)d_in[1];
  const float* b1  = (const float*)d_in[2];
  const float* lng = (const float*)d_in[3];
  const float* lnb = (const float*)d_in[4];
  const float* w2  = (const float*)d_in[5];
  const float* b2  = (const float*)d_in[6];
  float* out = (float*)d_out;

  const int inner = in_sizes[2];           // 8192
  const int d     = in_sizes[1] / inner;   // 2048
  const int M     = in_sizes[0] / d;       // 8192

  char* ws = (char*)d_ws;
  size_t off = 0;
  double* part = (double*)(ws + off); off += 1024 * 8;
  float*  fw   = (float*)(ws + off);  off += 256;
  float*  fx   = (float*)(ws + off);  off += (size_t)M * 4;
  float*  fh   = (float*)(ws + off);  off += (size_t)M * 4;
  char*   w1q  = ws + off;            off += (size_t)inner * d;
  char*   w2q  = ws + off;            off += (size_t)inner * d;

  // chunk: xq (MC*d i8) + h (MC*inner bf16) + hq (MC*inner i8)
  int MC = M;  // multiple of 256
  while (MC > 256 && off + (size_t)MC * ((size_t)d + 3 * (size_t)inner) > ws_size) MC >>= 1;
  char*   xq = ws + off;              off += (size_t)MC * d;
  bf16_t* h  = (bf16_t*)(ws + off);   off += (size_t)MC * inner * 2;
  char*   hq = ws + off;

  const int nw = inner * d;
  const int n4 = nw / 4;

  wabs_partial<<<1024, 256, 0, stream>>>(w1, n4, part);
  wabs_final<<<1, 256, 0, stream>>>(part, 1024, (double)nw, fw + 0);
  wabs_partial<<<1024, 256, 0, stream>>>(w2, n4, part);
  wabs_final<<<1, 256, 0, stream>>>(part, 1024, (double)nw, fw + 1);
  quant_w<<<n4 / 256, 256, 0, stream>>>(w1, fw + 0, w1q, n4);
  quant_w<<<n4 / 256, 256, 0, stream>>>(w2, fw + 1, w2q, n4);

  for (int mc = 0; mc < M; mc += MC) {
    rms_quant_x<<<MC, 256, 0, stream>>>(x + (size_t)mc * d, xq, fx, d);

    const int g1 = (MC / 256) * (inner / 256);
    gemm256<1, true><<<g1, 512, 0, stream>>>(xq, w1q, fx, fw + 0, b1,
                                             nullptr, h, MC, inner, d);

    ln_rms_quant<<<MC, 256, 0, stream>>>(h, hq, lng, lnb, fh, inner);

    const int g2 = (MC / 256) * (d / 256);
    gemm256<0, false><<<g2, 512, 0, stream>>>(hq, w2q, fh, fw + 1, b2,
                                              out + (size_t)mc * d, nullptr, MC, d, inner);
  }
}